// Round 1
// baseline (774.317 us; speedup 1.0000x reference)
//
#include <hip/hip_runtime.h>
#include <math.h>

// Problem constants
#define B_SZ 256
#define S_SZ 6
#define D_SZ 10000
#define DP   10112      // D padded to 158*64 (multiple of BK=64)
#define C_SZ 128
#define K_SZ 500
#define KP   512        // codebook rows padded
#define NIT  (DP / 64)  // 158 K-iterations

typedef _Float16     half8  __attribute__((ext_vector_type(8)));
typedef float        f32x4  __attribute__((ext_vector_type(4)));
typedef unsigned int u32x4v __attribute__((ext_vector_type(4)));

__device__ __forceinline__ void stage16(const void* g, void* l) {
    __builtin_amdgcn_global_load_lds(
        (const __attribute__((address_space(1))) unsigned int*)g,
        (__attribute__((address_space(3))) unsigned int*)l, 16, 0, 0);
}

// ---- prep: split W_reg (fp32) into f16 hi + f16 lo*4096 (2^-12 scale back at combine) ----
__global__ void prep_wsplit(const float* __restrict__ wreg,
                            _Float16* __restrict__ whi, _Float16* __restrict__ wlo) {
    int t = blockIdx.x * 256 + threadIdx.x;
    if (t >= C_SZ * DP) return;
    int c = t / DP, d = t - c * DP;
    float w = (d < D_SZ) ? wreg[c * D_SZ + d] : 0.0f;
    _Float16 hi = (_Float16)w;
    float r = w - (float)hi;           // exact in fp32
    _Float16 lo = (_Float16)(r * 4096.0f);  // pre-scale: keeps lo in normal f16 range
    whi[t] = hi;
    wlo[t] = lo;
}

// ---- prep: codebook (±1 fp32) -> f16, zero-padded to [512][DP] ----
__global__ void prep_cb(const float* __restrict__ cb, _Float16* __restrict__ cbp) {
    int t = blockIdx.x * 256 + threadIdx.x;
    if (t >= KP * DP) return;
    int k = t / DP, d = t - k * DP;
    float v = (k < K_SZ && d < D_SZ) ? cb[k * D_SZ + d] : 0.0f;
    cbp[t] = (_Float16)v;   // ±1 and 0 exact in f16
}

// ---- prep: enc sign mask (0x0000 = +1, 0x8000 = -1), fp64 for exact sign match ----
__global__ void prep_enc(const float* __restrict__ x, const float* __restrict__ wp,
                         const float* __restrict__ bp, unsigned short* __restrict__ em) {
    int t = blockIdx.x * 256 + threadIdx.x;
    if (t >= B_SZ * DP) return;
    int b = t / DP, d = t - b * DP;
    unsigned short m = 0;
    if (d < D_SZ) {
        double p = 0.0;
        #pragma unroll
        for (int s = 0; s < S_SZ; ++s)
            p += (double)x[b * S_SZ + s] * (double)wp[d * S_SZ + s];
        double hv = cos(p + (double)bp[d]) * sin(p);
        // jnp.where(hv > 0, 1, -1): hv>0 -> +1 (mask 0), else -1 (mask 0x8000)
        m = (hv > 0.0) ? (unsigned short)0u : (unsigned short)0x8000u;
    }
    em[t] = m;
}

// ---- main: per-(b, ntile) 128x128 GEMM tile over K=DP, fused partial argmax ----
// sim[b,c,k] = sum_d (±W[c,d]) * cb[k,d], sign from enc mask (XOR on f16 sign bit)
__global__ __launch_bounds__(256, 2) void gemm_argmax(
    const _Float16* __restrict__ whi, const _Float16* __restrict__ wlo,
    const _Float16* __restrict__ cbp, const unsigned short* __restrict__ em,
    float* __restrict__ pval, int* __restrict__ pidx)
{
    const int ntile = blockIdx.x;   // 0..3  (k-window of 128)
    const int b     = blockIdx.y;   // 0..255
    const int tid   = threadIdx.x;
    const int wave  = tid >> 6;
    const int lane  = tid & 63;
    const int quad  = lane >> 4;
    const int col   = lane & 15;
    const int wm    = (wave & 1) * 64;   // c offset of this wave's 64x64
    const int wn    = (wave >> 1) * 64;  // k offset

    __shared__ __align__(16) _Float16 s_whi[128 * 64];
    __shared__ __align__(16) _Float16 s_wlo[128 * 64];
    __shared__ __align__(16) _Float16 s_cb [128 * 64];
    __shared__ __align__(16) unsigned short s_mask[64];

    f32x4 acc_h[4][4], acc_l[4][4];
    #pragma unroll
    for (int i = 0; i < 4; ++i)
        #pragma unroll
        for (int j = 0; j < 4; ++j) {
            acc_h[i][j] = (f32x4){0.f, 0.f, 0.f, 0.f};
            acc_l[i][j] = (f32x4){0.f, 0.f, 0.f, 0.f};
        }

    const _Float16* cb_base = cbp + (size_t)(ntile * 128) * DP;
    const unsigned short* em_base = em + (size_t)b * DP;

    // staging geometry (8 f16 = 16 B per lane; LDS dest linear in thread id)
    int srow[4], scol[4], soff[4];
    #pragma unroll
    for (int s = 0; s < 4; ++s) {
        int e = s * 256 + tid;      // 0..1023 chunk index
        srow[s] = e >> 3;           // tile row 0..127
        scol[s] = (e & 7) * 8;      // f16 col within 64
        soff[s] = e * 8;            // f16 offset in LDS
    }

    for (int kb = 0; kb < NIT; ++kb) {
        const int k0 = kb * 64;
        #pragma unroll
        for (int s = 0; s < 4; ++s) {
            size_t go = (size_t)srow[s] * DP + (size_t)(k0 + scol[s]);
            stage16(whi + go,     s_whi + soff[s]);
            stage16(wlo + go,     s_wlo + soff[s]);
            stage16(cb_base + go, s_cb  + soff[s]);
        }
        if (tid < 8) {  // 64 ushorts = 128 B of sign masks for this K-block
            u32x4v mv = *(const u32x4v*)(em_base + k0 + tid * 8);
            *(u32x4v*)(s_mask + tid * 8) = mv;
        }
        __syncthreads();

        #pragma unroll
        for (int k2 = 0; k2 < 2; ++k2) {
            const int koff = k2 * 32 + quad * 8;  // k-range of this lane's fragment
            u32x4v mraw = *(const u32x4v*)(s_mask + koff);
            half8 bf[4];
            #pragma unroll
            for (int n = 0; n < 4; ++n)
                bf[n] = *(const half8*)(s_cb + (wn + n * 16 + col) * 64 + koff);
            #pragma unroll
            for (int m = 0; m < 4; ++m) {
                const int arow = (wm + m * 16 + col) * 64 + koff;
                u32x4v ah = *(const u32x4v*)(s_whi + arow) ^ mraw;
                u32x4v al = *(const u32x4v*)(s_wlo + arow) ^ mraw;
                half8 a_h = __builtin_bit_cast(half8, ah);
                half8 a_l = __builtin_bit_cast(half8, al);
                #pragma unroll
                for (int n = 0; n < 4; ++n) {
                    acc_h[m][n] = __builtin_amdgcn_mfma_f32_16x16x32_f16(a_h, bf[n], acc_h[m][n], 0, 0, 0);
                    acc_l[m][n] = __builtin_amdgcn_mfma_f32_16x16x32_f16(a_l, bf[n], acc_l[m][n], 0, 0, 0);
                }
            }
        }
        __syncthreads();
    }

    // ---- epilogue: partial argmax over this wg's 128-k window ----
    // C/D layout (16x16): col = lane&15 (k), row = quad*4 + reg (c)  [m89/m91 verified]
    float* sv = (float*)s_whi;   // [2][128]
    int*   si = (int*)s_wlo;     // [2][128]
    #pragma unroll
    for (int m = 0; m < 4; ++m) {
        #pragma unroll
        for (int r = 0; r < 4; ++r) {
            const int rowl = wm + m * 16 + quad * 4 + r;
            float bv = -3.0e38f; int bk = 0x7fffffff;
            #pragma unroll
            for (int n = 0; n < 4; ++n) {
                int kg = ntile * 128 + wn + n * 16 + col;
                float v = acc_h[m][n][r] + acc_l[m][n][r] * 0.000244140625f;  // + lo*2^-12
                if (kg < K_SZ && v > bv) { bv = v; bk = kg; }  // ascending kg: strict > keeps first max
            }
            #pragma unroll
            for (int off = 1; off < 16; off <<= 1) {
                float ov = __shfl_xor(bv, off, 64);
                int   ok = __shfl_xor(bk, off, 64);
                if (ov > bv || (ov == bv && ok < bk)) { bv = ov; bk = ok; }
            }
            if (col == 0) {
                sv[(wave >> 1) * 128 + rowl] = bv;
                si[(wave >> 1) * 128 + rowl] = bk;
            }
        }
    }
    __syncthreads();
    if (tid < 128) {
        float v0 = sv[tid], v1 = sv[128 + tid];
        int   i0 = si[tid], i1 = si[128 + tid];
        float bv; int bk;
        if (v1 > v0 || (v1 == v0 && i1 < i0)) { bv = v1; bk = i1; }
        else                                  { bv = v0; bk = i0; }
        int o = (b * 4 + ntile) * 128 + tid;
        pval[o] = bv;
        pidx[o] = bk;
    }
}

// ---- final: reduce 4 ntile partials per (b,c), map index -> temperature ----
__global__ void finalize_pred(const float* __restrict__ pval, const int* __restrict__ pidx,
                              float* __restrict__ out) {
    int t = blockIdx.x * 256 + threadIdx.x;
    if (t >= B_SZ * C_SZ) return;
    int b = t >> 7, c = t & 127;
    float bv = -3.0e38f; int bk = 0;
    #pragma unroll
    for (int nt = 0; nt < 4; ++nt) {
        int o = (b * 4 + nt) * 128 + c;
        float v = pval[o]; int k = pidx[o];
        if (v > bv || (v == bv && k < bk)) { bv = v; bk = k; }
    }
    out[t] = (float)bk / 499.0f * 61.5f + (-19.9f);  // idx/(L-1)*slope + MIN
}

extern "C" void kernel_launch(void* const* d_in, const int* in_sizes, int n_in,
                              void* d_out, int out_size, void* d_ws, size_t ws_size,
                              hipStream_t stream) {
    const float* x    = (const float*)d_in[0];
    const float* wp   = (const float*)d_in[1];
    const float* bp   = (const float*)d_in[2];
    const float* wreg = (const float*)d_in[3];
    const float* cb   = (const float*)d_in[4];
    float* out = (float*)d_out;

    char* ws = (char*)d_ws;
    size_t o = 0;
    auto take = [&](size_t bytes) -> char* {
        o = (o + 255) & ~(size_t)255;
        char* p = ws + o;
        o += bytes;
        return p;
    };
    _Float16* whi       = (_Float16*)take(sizeof(_Float16) * C_SZ * DP);
    _Float16* wlo       = (_Float16*)take(sizeof(_Float16) * C_SZ * DP);
    _Float16* cbp       = (_Float16*)take(sizeof(_Float16) * KP * DP);
    unsigned short* em  = (unsigned short*)take(sizeof(unsigned short) * B_SZ * DP);
    float* pv           = (float*)take(sizeof(float) * B_SZ * 4 * C_SZ);
    int*   pi           = (int*)take(sizeof(int) * B_SZ * 4 * C_SZ);
    (void)ws_size; (void)in_sizes; (void)n_in; (void)out_size;

    prep_wsplit<<<(C_SZ * DP + 255) / 256, 256, 0, stream>>>(wreg, whi, wlo);
    prep_cb<<<(KP * DP + 255) / 256, 256, 0, stream>>>(cb, cbp);
    prep_enc<<<(B_SZ * DP + 255) / 256, 256, 0, stream>>>(x, wp, bp, em);

    dim3 g(4, B_SZ);
    gemm_argmax<<<g, 256, 0, stream>>>(whi, wlo, cbp, em, pv, pi);

    finalize_pred<<<(B_SZ * C_SZ + 255) / 256, 256, 0, stream>>>(pv, pi, out);
}

// Round 2
// 692.012 us; speedup vs baseline: 1.1189x; 1.1189x over previous
//
#include <hip/hip_runtime.h>
#include <math.h>

// Problem constants
#define B_SZ 256
#define S_SZ 6
#define D_SZ 10000
#define DP   10112      // D padded to 158*64 (multiple of BK=64)
#define C_SZ 128
#define K_SZ 500
#define KP   512        // codebook rows padded
#define NIT  (DP / 64)  // 158 K-iterations

typedef _Float16     half8  __attribute__((ext_vector_type(8)));
typedef float        f32x4  __attribute__((ext_vector_type(4)));
typedef unsigned int u32x4v __attribute__((ext_vector_type(4)));

__device__ __forceinline__ void stage16(const void* g, void* l) {
    __builtin_amdgcn_global_load_lds(
        (const __attribute__((address_space(1))) unsigned int*)g,
        (__attribute__((address_space(3))) unsigned int*)l, 16, 0, 0);
}

// ---- prep: split W_reg (fp32) into f16 hi + f16 lo*4096 (2^-12 scale back at combine) ----
__global__ void prep_wsplit(const float* __restrict__ wreg,
                            _Float16* __restrict__ whi, _Float16* __restrict__ wlo) {
    int t = blockIdx.x * 256 + threadIdx.x;
    if (t >= C_SZ * DP) return;
    int c = t / DP, d = t - c * DP;
    float w = (d < D_SZ) ? wreg[c * D_SZ + d] : 0.0f;
    _Float16 hi = (_Float16)w;
    float r = w - (float)hi;           // exact in fp32
    _Float16 lo = (_Float16)(r * 4096.0f);  // pre-scale: keeps lo in normal f16 range
    whi[t] = hi;
    wlo[t] = lo;
}

// ---- prep: codebook (±1 fp32) -> f16, zero-padded to [512][DP] ----
__global__ void prep_cb(const float* __restrict__ cb, _Float16* __restrict__ cbp) {
    int t = blockIdx.x * 256 + threadIdx.x;
    if (t >= KP * DP) return;
    int k = t / DP, d = t - k * DP;
    float v = (k < K_SZ && d < D_SZ) ? cb[k * D_SZ + d] : 0.0f;
    cbp[t] = (_Float16)v;   // ±1 and 0 exact in f16
}

// ---- prep: enc sign mask (0x0000 = +1, 0x8000 = -1), fp64 for exact sign match ----
__global__ void prep_enc(const float* __restrict__ x, const float* __restrict__ wp,
                         const float* __restrict__ bp, unsigned short* __restrict__ em) {
    int t = blockIdx.x * 256 + threadIdx.x;
    if (t >= B_SZ * DP) return;
    int b = t / DP, d = t - b * DP;
    unsigned short m = 0;
    if (d < D_SZ) {
        double p = 0.0;
        #pragma unroll
        for (int s = 0; s < S_SZ; ++s)
            p += (double)x[b * S_SZ + s] * (double)wp[d * S_SZ + s];
        double hv = cos(p + (double)bp[d]) * sin(p);
        m = (hv > 0.0) ? (unsigned short)0u : (unsigned short)0x8000u;
    }
    em[t] = m;
}

// ---- main: per-(b, ntile) 128x128 GEMM tile over K=DP, fused partial argmax ----
// sim[b,c,k] = sum_d (±W[c,d]) * cb[k,d], sign from enc mask (XOR on f16 sign bit)
// LDS layout XOR-swizzled: 16-B chunk p of row r holds logical chunk (p ^ (r&7)),
// so row-parallel fragment reads hit all 32 banks (was: 8-way conflict, 1.9e8 cycles).
__global__ __launch_bounds__(256, 2) void gemm_argmax(
    const _Float16* __restrict__ whi, const _Float16* __restrict__ wlo,
    const _Float16* __restrict__ cbp, const unsigned short* __restrict__ em,
    float* __restrict__ pval, int* __restrict__ pidx)
{
    const int ntile = blockIdx.x;   // 0..3  (k-window of 128)
    const int b     = blockIdx.y;   // 0..255
    const int tid   = threadIdx.x;
    const int wave  = tid >> 6;
    const int lane  = tid & 63;
    const int quad  = lane >> 4;
    const int col   = lane & 15;
    const int wm    = (wave & 1) * 64;   // c offset of this wave's 64x64
    const int wn    = (wave >> 1) * 64;  // k offset

    __shared__ __align__(16) _Float16 s_whi[128 * 64];
    __shared__ __align__(16) _Float16 s_wlo[128 * 64];
    __shared__ __align__(16) _Float16 s_cb [128 * 64];
    __shared__ __align__(16) unsigned short s_mask[64];

    f32x4 acc_h[4][4], acc_l[4][4];
    #pragma unroll
    for (int i = 0; i < 4; ++i)
        #pragma unroll
        for (int j = 0; j < 4; ++j) {
            acc_h[i][j] = (f32x4){0.f, 0.f, 0.f, 0.f};
            acc_l[i][j] = (f32x4){0.f, 0.f, 0.f, 0.f};
        }

    const _Float16* cb_base = cbp + (size_t)(ntile * 128) * DP;
    const unsigned short* em_base = em + (size_t)b * DP;

    // staging geometry: slot e holds row=e>>3, chunk-pos p=e&7; global chunk = p^(row&7)
    int srow[4], sgcol[4], soff[4];
    #pragma unroll
    for (int s = 0; s < 4; ++s) {
        int e = s * 256 + tid;            // 0..1023 chunk slot
        int row = e >> 3;
        int p   = e & 7;
        srow[s]  = row;
        sgcol[s] = (p ^ (row & 7)) * 8;   // swizzled global f16 col within 64
        soff[s]  = e * 8;                 // linear f16 offset in LDS (HW requirement)
    }

    for (int kb = 0; kb < NIT; ++kb) {
        const int k0 = kb * 64;
        #pragma unroll
        for (int s = 0; s < 4; ++s) {
            size_t go = (size_t)srow[s] * DP + (size_t)(k0 + sgcol[s]);
            stage16(whi + go,     s_whi + soff[s]);
            stage16(wlo + go,     s_wlo + soff[s]);
            stage16(cb_base + go, s_cb  + soff[s]);
        }
        if (tid < 8) {  // 64 ushorts = 128 B of sign masks for this K-block
            u32x4v mv = *(const u32x4v*)(em_base + k0 + tid * 8);
            *(u32x4v*)(s_mask + tid * 8) = mv;
        }
        __syncthreads();

        #pragma unroll
        for (int k2 = 0; k2 < 2; ++k2) {
            const int chunk = k2 * 4 + quad;          // logical 16-B chunk (k-range)
            const int koff  = chunk * 8;              // logical f16 offset (for mask)
            const int sw    = (chunk ^ (col & 7)) * 8; // swizzled LDS offset:
            // all fragment rows are (mult-of-16 + col), so row&7 == col&7
            u32x4v mraw = *(const u32x4v*)(s_mask + koff);
            half8 bf[4];
            #pragma unroll
            for (int n = 0; n < 4; ++n)
                bf[n] = *(const half8*)(s_cb + (wn + n * 16 + col) * 64 + sw);
            #pragma unroll
            for (int m = 0; m < 4; ++m) {
                const int arow = (wm + m * 16 + col) * 64 + sw;
                u32x4v ah = *(const u32x4v*)(s_whi + arow) ^ mraw;
                u32x4v al = *(const u32x4v*)(s_wlo + arow) ^ mraw;
                half8 a_h = __builtin_bit_cast(half8, ah);
                half8 a_l = __builtin_bit_cast(half8, al);
                #pragma unroll
                for (int n = 0; n < 4; ++n) {
                    acc_h[m][n] = __builtin_amdgcn_mfma_f32_16x16x32_f16(a_h, bf[n], acc_h[m][n], 0, 0, 0);
                    acc_l[m][n] = __builtin_amdgcn_mfma_f32_16x16x32_f16(a_l, bf[n], acc_l[m][n], 0, 0, 0);
                }
            }
        }
        __syncthreads();
    }

    // ---- epilogue: partial argmax over this wg's 128-k window ----
    // C/D layout (16x16): col = lane&15 (k), row = quad*4 + reg (c)  [m89/m91 verified]
    float* sv = (float*)s_whi;   // [2][128]
    int*   si = (int*)s_wlo;     // [2][128]
    #pragma unroll
    for (int m = 0; m < 4; ++m) {
        #pragma unroll
        for (int r = 0; r < 4; ++r) {
            const int rowl = wm + m * 16 + quad * 4 + r;
            float bv = -3.0e38f; int bk = 0x7fffffff;
            #pragma unroll
            for (int n = 0; n < 4; ++n) {
                int kg = ntile * 128 + wn + n * 16 + col;
                float v = acc_h[m][n][r] + acc_l[m][n][r] * 0.000244140625f;  // + lo*2^-12
                if (kg < K_SZ && v > bv) { bv = v; bk = kg; }  // ascending kg: strict > keeps first max
            }
            #pragma unroll
            for (int off = 1; off < 16; off <<= 1) {
                float ov = __shfl_xor(bv, off, 64);
                int   ok = __shfl_xor(bk, off, 64);
                if (ov > bv || (ov == bv && ok < bk)) { bv = ov; bk = ok; }
            }
            if (col == 0) {
                sv[(wave >> 1) * 128 + rowl] = bv;
                si[(wave >> 1) * 128 + rowl] = bk;
            }
        }
    }
    __syncthreads();
    if (tid < 128) {
        float v0 = sv[tid], v1 = sv[128 + tid];
        int   i0 = si[tid], i1 = si[128 + tid];
        float bv; int bk;
        if (v1 > v0 || (v1 == v0 && i1 < i0)) { bv = v1; bk = i1; }
        else                                  { bv = v0; bk = i0; }
        int o = (b * 4 + ntile) * 128 + tid;
        pval[o] = bv;
        pidx[o] = bk;
    }
}

// ---- final: reduce 4 ntile partials per (b,c), map index -> temperature ----
__global__ void finalize_pred(const float* __restrict__ pval, const int* __restrict__ pidx,
                              float* __restrict__ out) {
    int t = blockIdx.x * 256 + threadIdx.x;
    if (t >= B_SZ * C_SZ) return;
    int b = t >> 7, c = t & 127;
    float bv = -3.0e38f; int bk = 0;
    #pragma unroll
    for (int nt = 0; nt < 4; ++nt) {
        int o = (b * 4 + nt) * 128 + c;
        float v = pval[o]; int k = pidx[o];
        if (v > bv || (v == bv && k < bk)) { bv = v; bk = k; }
    }
    out[t] = (float)bk / 499.0f * 61.5f + (-19.9f);  // idx/(L-1)*slope + MIN
}

extern "C" void kernel_launch(void* const* d_in, const int* in_sizes, int n_in,
                              void* d_out, int out_size, void* d_ws, size_t ws_size,
                              hipStream_t stream) {
    const float* x    = (const float*)d_in[0];
    const float* wp   = (const float*)d_in[1];
    const float* bp   = (const float*)d_in[2];
    const float* wreg = (const float*)d_in[3];
    const float* cb   = (const float*)d_in[4];
    float* out = (float*)d_out;

    char* ws = (char*)d_ws;
    size_t o = 0;
    auto take = [&](size_t bytes) -> char* {
        o = (o + 255) & ~(size_t)255;
        char* p = ws + o;
        o += bytes;
        return p;
    };
    _Float16* whi       = (_Float16*)take(sizeof(_Float16) * C_SZ * DP);
    _Float16* wlo       = (_Float16*)take(sizeof(_Float16) * C_SZ * DP);
    _Float16* cbp       = (_Float16*)take(sizeof(_Float16) * KP * DP);
    unsigned short* em  = (unsigned short*)take(sizeof(unsigned short) * B_SZ * DP);
    float* pv           = (float*)take(sizeof(float) * B_SZ * 4 * C_SZ);
    int*   pi           = (int*)take(sizeof(int) * B_SZ * 4 * C_SZ);
    (void)ws_size; (void)in_sizes; (void)n_in; (void)out_size;

    prep_wsplit<<<(C_SZ * DP + 255) / 256, 256, 0, stream>>>(wreg, whi, wlo);
    prep_cb<<<(KP * DP + 255) / 256, 256, 0, stream>>>(cb, cbp);
    prep_enc<<<(B_SZ * DP + 255) / 256, 256, 0, stream>>>(x, wp, bp, em);

    dim3 g(4, B_SZ);
    gemm_argmax<<<g, 256, 0, stream>>>(whi, wlo, cbp, em, pv, pi);

    finalize_pred<<<(B_SZ * C_SZ + 255) / 256, 256, 0, stream>>>(pv, pi, out);
}

// Round 3
// 590.830 us; speedup vs baseline: 1.3106x; 1.1713x over previous
//
#include <hip/hip_runtime.h>
#include <math.h>

// Problem constants
#define B_SZ 256
#define S_SZ 6
#define D_SZ 10000
#define DP   10112      // D padded to 158*64
#define C_SZ 128
#define K_SZ 500
#define KP   512        // codebook rows padded (8 k-tiles of 64)
#define NIT  (DP / 64)  // 158 K-iterations

typedef _Float16     half8  __attribute__((ext_vector_type(8)));
typedef float        f32x4  __attribute__((ext_vector_type(4)));
typedef unsigned int u32x4v __attribute__((ext_vector_type(4)));

__device__ __forceinline__ void stage16(const void* g, void* l) {
    __builtin_amdgcn_global_load_lds(
        (const __attribute__((address_space(1))) unsigned int*)g,
        (__attribute__((address_space(3))) unsigned int*)l, 16, 0, 0);
}

// ---- prep: split W_reg (fp32) into f16 hi + f16 lo*4096 ----
__global__ void prep_wsplit(const float* __restrict__ wreg,
                            _Float16* __restrict__ whi, _Float16* __restrict__ wlo) {
    int t = blockIdx.x * 256 + threadIdx.x;
    if (t >= C_SZ * DP) return;
    int c = t / DP, d = t - c * DP;
    float w = (d < D_SZ) ? wreg[c * D_SZ + d] : 0.0f;
    _Float16 hi = (_Float16)w;
    float r = w - (float)hi;
    _Float16 lo = (_Float16)(r * 4096.0f);
    whi[t] = hi;
    wlo[t] = lo;
}

// ---- prep: codebook (±1 fp32) -> f16, zero-padded to [512][DP] ----
__global__ void prep_cb(const float* __restrict__ cb, _Float16* __restrict__ cbp) {
    int t = blockIdx.x * 256 + threadIdx.x;
    if (t >= KP * DP) return;
    int k = t / DP, d = t - k * DP;
    float v = (k < K_SZ && d < D_SZ) ? cb[k * D_SZ + d] : 0.0f;
    cbp[t] = (_Float16)v;
}

// ---- prep: enc sign mask (0x0000 = +1, 0x8000 = -1), fp64 for exact sign match ----
__global__ void prep_enc(const float* __restrict__ x, const float* __restrict__ wp,
                         const float* __restrict__ bp, unsigned short* __restrict__ em) {
    int t = blockIdx.x * 256 + threadIdx.x;
    if (t >= B_SZ * DP) return;
    int b = t / DP, d = t - b * DP;
    unsigned short m = 0;
    if (d < D_SZ) {
        double p = 0.0;
        #pragma unroll
        for (int s = 0; s < S_SZ; ++s)
            p += (double)x[b * S_SZ + s] * (double)wp[d * S_SZ + s];
        double hv = cos(p + (double)bp[d]) * sin(p);
        m = (hv > 0.0) ? (unsigned short)0u : (unsigned short)0x8000u;
    }
    em[t] = m;
}

// ---- main: block = 4 batches x 64c x 64k; staged A/B tiles are batch-independent,
// signs XORed onto B fragments (bit-exact: a*(s*b) = s*(a*b)). 4x LDS/staging reuse.
// LDS XOR-swizzled: 16-B chunk p of row r holds logical chunk (p ^ (r&7)).
__global__ __launch_bounds__(256, 2) void gemm_argmax(
    const _Float16* __restrict__ whi, const _Float16* __restrict__ wlo,
    const _Float16* __restrict__ cbp, const unsigned short* __restrict__ em,
    float* __restrict__ pval, int* __restrict__ pidx)
{
    const int kt = blockIdx.x >> 1;   // 0..7  k-tile (64 codebook rows)
    const int ct = blockIdx.x & 1;    // 0..1  c-tile (64 classes)
    const int bg = blockIdx.y;        // 0..63 batch group (4 batches)
    const int tid  = threadIdx.x;
    const int wave = tid >> 6;
    const int lane = tid & 63;
    const int quad = lane >> 4;
    const int col  = lane & 15;
    const int ch32 = (wave & 1) * 32;   // c offset of this wave's 32x32-per-b
    const int kh32 = (wave >> 1) * 32;  // k offset

    __shared__ __align__(16) _Float16 s_whi[64 * 64];
    __shared__ __align__(16) _Float16 s_wlo[64 * 64];
    __shared__ __align__(16) _Float16 s_cb [64 * 64];
    __shared__ __align__(16) unsigned short s_mask[4 * 64];

    f32x4 acc_h[4][2][2], acc_l[4][2][2];
    #pragma unroll
    for (int b = 0; b < 4; ++b)
        #pragma unroll
        for (int m = 0; m < 2; ++m)
            #pragma unroll
            for (int n = 0; n < 2; ++n) {
                acc_h[b][m][n] = (f32x4){0.f, 0.f, 0.f, 0.f};
                acc_l[b][m][n] = (f32x4){0.f, 0.f, 0.f, 0.f};
            }

    const int c0  = ct * 64;
    const int kr0 = kt * 64;
    const int bg4 = bg * 4;

    // staging geometry: slot e: row=e>>3, pos p=e&7; global chunk = p^(row&7)
    size_t abase[2], bbase[2];
    int soff[2];
    #pragma unroll
    for (int s = 0; s < 2; ++s) {
        int e = s * 256 + tid;          // 0..511
        int row = e >> 3;
        int p = e & 7;
        int gcol = (p ^ (row & 7)) * 8;
        abase[s] = (size_t)(c0 + row) * DP + gcol;
        bbase[s] = (size_t)(kr0 + row) * DP + gcol;
        soff[s] = e * 8;
    }

    for (int kb = 0; kb < NIT; ++kb) {
        const int k0 = kb * 64;
        #pragma unroll
        for (int s = 0; s < 2; ++s) {
            stage16(whi + abase[s] + k0, s_whi + soff[s]);
            stage16(wlo + abase[s] + k0, s_wlo + soff[s]);
            stage16(cbp + bbase[s] + k0, s_cb  + soff[s]);
        }
        if (tid < 32) {  // 4 b x 64 ushort masks = 512 B
            const u32x4v mv = *(const u32x4v*)(em + (size_t)(bg4 + (tid >> 3)) * DP + k0 + (tid & 7) * 8);
            *(u32x4v*)(s_mask + (tid >> 3) * 64 + (tid & 7) * 8) = mv;
        }
        __syncthreads();

        // load both k2 phases' fragments up front: phase-1 loads stay in flight
        // (lgkmcnt>0) while phase-0 MFMAs run.
        u32x4v ah[2][2], al[2][2], br[2][2], mr[2][4];
        #pragma unroll
        for (int k2 = 0; k2 < 2; ++k2) {
            const int chunk = k2 * 4 + quad;
            const int koff  = chunk * 8;
            const int sw    = (chunk ^ (col & 7)) * 8;
            #pragma unroll
            for (int m = 0; m < 2; ++m) {
                ah[k2][m] = *(const u32x4v*)(s_whi + (ch32 + m * 16 + col) * 64 + sw);
                al[k2][m] = *(const u32x4v*)(s_wlo + (ch32 + m * 16 + col) * 64 + sw);
            }
            #pragma unroll
            for (int n = 0; n < 2; ++n)
                br[k2][n] = *(const u32x4v*)(s_cb + (kh32 + n * 16 + col) * 64 + sw);
            #pragma unroll
            for (int b = 0; b < 4; ++b)
                mr[k2][b] = *(const u32x4v*)(s_mask + b * 64 + koff);
        }
        #pragma unroll
        for (int k2 = 0; k2 < 2; ++k2) {
            #pragma unroll
            for (int b = 0; b < 4; ++b) {
                half8 bs[2];
                #pragma unroll
                for (int n = 0; n < 2; ++n)
                    bs[n] = __builtin_bit_cast(half8, br[k2][n] ^ mr[k2][b]);
                #pragma unroll
                for (int m = 0; m < 2; ++m) {
                    half8 a_h = __builtin_bit_cast(half8, ah[k2][m]);
                    half8 a_l = __builtin_bit_cast(half8, al[k2][m]);
                    #pragma unroll
                    for (int n = 0; n < 2; ++n) {
                        acc_h[b][m][n] = __builtin_amdgcn_mfma_f32_16x16x32_f16(a_h, bs[n], acc_h[b][m][n], 0, 0, 0);
                        acc_l[b][m][n] = __builtin_amdgcn_mfma_f32_16x16x32_f16(a_l, bs[n], acc_l[b][m][n], 0, 0, 0);
                    }
                }
            }
        }
        __syncthreads();
    }

    // ---- epilogue: partial argmax over this block's 64-k window, per (b, c) ----
    // C/D layout (16x16): col = lane&15 (k), row = quad*4 + reg (c)
    float* sv = (float*)s_whi;   // [kh 2][b 4][c 64]
    int*   si = (int*)s_wlo;
    #pragma unroll
    for (int b = 0; b < 4; ++b) {
        #pragma unroll
        for (int m = 0; m < 2; ++m) {
            #pragma unroll
            for (int r = 0; r < 4; ++r) {
                const int crow = ch32 + m * 16 + quad * 4 + r;  // 0..63
                float bv = -3.0e38f; int bk = 0x7fffffff;
                #pragma unroll
                for (int n = 0; n < 2; ++n) {
                    int kg = kr0 + kh32 + n * 16 + col;
                    float v = acc_h[b][m][n][r] + acc_l[b][m][n][r] * 0.000244140625f;
                    if (kg < K_SZ && v > bv) { bv = v; bk = kg; }
                }
                #pragma unroll
                for (int off = 1; off < 16; off <<= 1) {
                    float ov = __shfl_xor(bv, off, 64);
                    int   ok = __shfl_xor(bk, off, 64);
                    if (ov > bv || (ov == bv && ok < bk)) { bv = ov; bk = ok; }
                }
                if (col == 0) {
                    int o = ((wave >> 1) * 4 + b) * 64 + crow;
                    sv[o] = bv;
                    si[o] = bk;
                }
            }
        }
    }
    __syncthreads();
    {
        int b = tid >> 6, c = tid & 63;
        int o0 = b * 64 + c, o1 = (4 + b) * 64 + c;
        float v0 = sv[o0], v1 = sv[o1];
        int   i0 = si[o0], i1 = si[o1];
        float bv; int bk;
        if (v1 > v0 || (v1 == v0 && i1 < i0)) { bv = v1; bk = i1; }
        else                                  { bv = v0; bk = i0; }
        int o = ((bg4 + b) * 8 + kt) * 128 + (c0 + c);
        pval[o] = bv;
        pidx[o] = bk;
    }
}

// ---- final: reduce 8 kt partials per (b,c), map index -> temperature ----
__global__ void finalize_pred(const float* __restrict__ pval, const int* __restrict__ pidx,
                              float* __restrict__ out) {
    int t = blockIdx.x * 256 + threadIdx.x;
    if (t >= B_SZ * C_SZ) return;
    int b = t >> 7, c = t & 127;
    float bv = -3.0e38f; int bk = 0;
    #pragma unroll
    for (int nt = 0; nt < 8; ++nt) {
        int o = (b * 8 + nt) * 128 + c;
        float v = pval[o]; int k = pidx[o];
        if (v > bv || (v == bv && k < bk)) { bv = v; bk = k; }
    }
    out[t] = (float)bk / 499.0f * 61.5f + (-19.9f);
}

extern "C" void kernel_launch(void* const* d_in, const int* in_sizes, int n_in,
                              void* d_out, int out_size, void* d_ws, size_t ws_size,
                              hipStream_t stream) {
    const float* x    = (const float*)d_in[0];
    const float* wp   = (const float*)d_in[1];
    const float* bp   = (const float*)d_in[2];
    const float* wreg = (const float*)d_in[3];
    const float* cb   = (const float*)d_in[4];
    float* out = (float*)d_out;

    char* ws = (char*)d_ws;
    size_t o = 0;
    auto take = [&](size_t bytes) -> char* {
        o = (o + 255) & ~(size_t)255;
        char* p = ws + o;
        o += bytes;
        return p;
    };
    _Float16* whi       = (_Float16*)take(sizeof(_Float16) * C_SZ * DP);
    _Float16* wlo       = (_Float16*)take(sizeof(_Float16) * C_SZ * DP);
    _Float16* cbp       = (_Float16*)take(sizeof(_Float16) * KP * DP);
    unsigned short* em  = (unsigned short*)take(sizeof(unsigned short) * B_SZ * DP);
    float* pv           = (float*)take(sizeof(float) * B_SZ * 8 * C_SZ);
    int*   pi           = (int*)take(sizeof(int) * B_SZ * 8 * C_SZ);
    (void)ws_size; (void)in_sizes; (void)n_in; (void)out_size;

    prep_wsplit<<<(C_SZ * DP + 255) / 256, 256, 0, stream>>>(wreg, whi, wlo);
    prep_cb<<<(KP * DP + 255) / 256, 256, 0, stream>>>(cb, cbp);
    prep_enc<<<(B_SZ * DP + 255) / 256, 256, 0, stream>>>(x, wp, bp, em);

    dim3 g(16, 64);  // x: kt*2+ct, y: batch group
    gemm_argmax<<<g, 256, 0, stream>>>(whi, wlo, cbp, em, pv, pi);

    finalize_pred<<<(B_SZ * C_SZ + 255) / 256, 256, 0, stream>>>(pv, pi, out);
}